// Round 13
// baseline (947.182 us; speedup 1.0000x reference)
//
#include <hip/hip_runtime.h>
#include <math.h>

#define B_     64
#define N_     128
#define FIN_   128
#define H_     512
#define MSG_   512
#define L_     4
#define NSTEPS_ 4
#define TGT_   12
#define ROWS_  (B_*N_)   // 8192

typedef _Float16 f16;
typedef __attribute__((ext_vector_type(8))) _Float16 half8;
typedef __attribute__((ext_vector_type(4))) float f32x4;

__device__ inline void gload16(const void* g, void* l) {
    __builtin_amdgcn_global_load_lds((const __attribute__((address_space(1))) void*)g,
                                     (__attribute__((address_space(3))) void*)l,
                                     16, 0, 0);
}

__device__ inline void split_write(float v, f16* ph, f16* pl) {
    f16 hi = (f16)v;
    *ph = hi;
    *pl = (f16)(v - (float)hi);
}

// ---------------------------------------------------------------------------
// init: hb0 planes [8192][1024]: cols 0-511 = h (=h0), cols 512-1023 = h0
// ---------------------------------------------------------------------------
__global__ void k_init(const float* __restrict__ h_in,
                       f16* __restrict__ hbh, f16* __restrict__ hbl,
                       float* __restrict__ nmask, float* __restrict__ rmask) {
    int bn = blockIdx.x;
    int t  = threadIdx.x;           // 0..127
    const float* src = h_in + (size_t)bn * FIN_;
    float v  = src[t];
    float sa = fabsf(v), ss = v;
    #pragma unroll
    for (int o = 32; o > 0; o >>= 1) {
        sa += __shfl_down(sa, o);
        ss += __shfl_down(ss, o);
    }
    __shared__ float wa[2], wsum[2];
    int wid = t >> 6, lane = t & 63;
    if (lane == 0) { wa[wid] = sa; wsum[wid] = ss; }
    __syncthreads();
    if (t == 0) {
        float ta = wa[0] + wa[1], ts = wsum[0] + wsum[1];
        nmask[bn] = (ta > 0.f) ? 1.f : 0.f;
        rmask[bn] = (ts != 0.f) ? 1.f : 0.f;
    }
    f16* bh = hbh + (size_t)bn * 1024;
    f16* bl = hbl + (size_t)bn * 1024;
    #pragma unroll
    for (int r = 0; r < 4; r++) {
        int j = t + r * 128;
        float val = (j < FIN_) ? src[j] : 0.f;
        f16 hi = (f16)val, lo = (f16)(val - (float)hi);
        bh[j] = hi; bl[j] = lo;
        bh[512 + j] = hi; bl[512 + j] = lo;
    }
}

// ---------------------------------------------------------------------------
// binary edge-label mask M[b*128+v][l*128+w] = g * [e == l+1]  (exact f16)
// ---------------------------------------------------------------------------
__global__ void k_mkmask(const float* __restrict__ g, const float* __restrict__ e,
                         f16* __restrict__ Mm) {
    long idx = (long)blockIdx.x * 256 + threadIdx.x;
    if (idx >= (long)ROWS_ * 512) return;
    int w = idx & 127;
    int l = (idx >> 7) & 3;
    long bv = idx >> 9;
    float gv = g[bv * N_ + w];
    float ev = e[bv * N_ + w];
    Mm[idx] = (f16)((gv != 0.f && (int)ev == l + 1) ? 1.f : 0.f);
}

// ---------------------------------------------------------------------------
// fused weight conversion: 10 tensors, hi-plane only, zero row-padding.
// ---------------------------------------------------------------------------
struct WSet {
    const float* s[10];
    f16* d[10];
    int nc[10];
    int ncp[10];
    int kk[10];
};
__global__ void k_convWs(WSet ws) {
    int ti = blockIdx.y;
    long idx = (long)blockIdx.x * 256 + threadIdx.x;
    int K = ws.kk[ti];
    long tot = (long)ws.ncp[ti] * K;
    if (idx >= tot) return;
    long n = idx / K;
    ws.d[ti][idx] = (f16)((n < ws.nc[ti]) ? ws.s[ti][idx] : 0.f);
}

// A [2048][512] fp32 -> AT hi [512][2048]
__global__ void k_convA(const float* __restrict__ A, f16* __restrict__ ATh) {
    long idx = (long)blockIdx.x * 256 + threadIdx.x;   // n*2048 + k
    long n = idx >> 11, k = idx & 2047;
    ATh[idx] = (f16)A[k * 512 + n];
}

// ---------------------------------------------------------------------------
// k_proj (1-pass, hi-only out): hAT_l[j][wg] = sum_h ATh[j][lh] * hb_hi[wg][h]
// out per-batch layout: o[((wg>>7)*512 + j)*512 + l*128 + (wg&127)] hi
// ---------------------------------------------------------------------------
__global__ __launch_bounds__(256, 4)
void k_proj(const f16* __restrict__ ATh, const f16* __restrict__ hb,
            f16* __restrict__ oh)
{
    __shared__ __align__(16) f16 As[2][4][128][8];   // 16KB  AT hi
    __shared__ __align__(16) f16 Bs[2][4][128][8];   // 16KB  hb
    const int tid = threadIdx.x;
    const int l = tid & 63, w = tid >> 6;
    const int wr = w >> 1, wc = w & 1;
    const int lz = blockIdx.z;
    const long m0 = (long)blockIdx.x * 128;     // j
    const long n0 = (long)blockIdx.y * 128;     // wg

    f32x4 acc[4][4];
    #pragma unroll
    for (int i = 0; i < 4; i++)
        #pragma unroll
        for (int j = 0; j < 4; j++)
            acc[i][j] = (f32x4){0.f, 0.f, 0.f, 0.f};

    const int nt = 512 >> 5;

    auto stage = [&](int buf, int t) {
        long k0 = (long)t << 5;
        #pragma unroll
        for (int i = 0; i < 2; ++i) {
            int la = tid + i * 256;
            int row = la & 127, c = la >> 7;
            gload16(ATh + (m0 + row) * 2048 + lz * 512 + k0 + c * 8,
                    (f16*)As[buf] + (size_t)la * 8);
        }
        #pragma unroll
        for (int i = 0; i < 2; ++i) {
            int la = tid + i * 256;
            int col = la & 127, c = la >> 7;
            gload16(hb + (n0 + col) * 1024 + k0 + c * 8,
                    (f16*)Bs[buf] + (size_t)la * 8);
        }
    };

    stage(0, 0);
    for (int t = 0; t < nt; ++t) {
        int cur = t & 1;
        __syncthreads();
        if (t + 1 < nt) stage(cur ^ 1, t + 1);
        const int g = l >> 4, idx = l & 15;
        half8 bf[4];
        #pragma unroll
        for (int ct = 0; ct < 4; ++ct)
            bf[ct] = *(const half8*)&Bs[cur][g][wc * 64 + ct * 16 + idx][0];
        #pragma unroll
        for (int rt = 0; rt < 4; ++rt) {
            half8 ah = *(const half8*)&As[cur][g][wr * 64 + rt * 16 + idx][0];
            #pragma unroll
            for (int ct = 0; ct < 4; ++ct)
                acc[rt][ct] = __builtin_amdgcn_mfma_f32_16x16x32_f16(ah, bf[ct], acc[rt][ct], 0, 0, 0);
        }
    }

    #pragma unroll
    for (int rt = 0; rt < 4; ++rt)
        #pragma unroll
        for (int ct = 0; ct < 4; ++ct) {
            long col = n0 + wc * 64 + ct * 16 + (l & 15);
            long bb = col >> 7, ww = col & 127;
            #pragma unroll
            for (int j = 0; j < 4; ++j) {
                long row = m0 + wr * 64 + rt * 16 + (l >> 4) * 4 + j;
                size_t o = ((size_t)(bb * 512 + row)) * 512 + lz * 128 + ww;
                oh[o] = (f16)acc[rt][ct][j];
            }
        }
}

// ---------------------------------------------------------------------------
// k_aggm (single-plane): m_hi[b*128+v][j] = sum_lw M[b][v][lw] * hATh[b][j][lw]
// 32KB LDS -> 4 blocks/CU.
// ---------------------------------------------------------------------------
__global__ __launch_bounds__(256, 4)
void k_aggm(const f16* __restrict__ Mm, const f16* __restrict__ ph,
            f16* __restrict__ mh)
{
    __shared__ __align__(16) f16 As[2][4][128][8];   // 16KB  M
    __shared__ __align__(16) f16 Bs[2][4][128][8];   // 16KB  hAT hi
    const int tid = threadIdx.x;
    const int l = tid & 63, w = tid >> 6;
    const int wr = w >> 1, wc = w & 1;
    const long b  = blockIdx.y;
    const long n0 = (long)blockIdx.x * 128;
    const f16* Xb = Mm + (size_t)b * 128 * 512;
    const f16* W0 = ph + (size_t)b * 512 * 512;

    f32x4 acc[4][4];
    #pragma unroll
    for (int i = 0; i < 4; i++)
        #pragma unroll
        for (int j = 0; j < 4; j++)
            acc[i][j] = (f32x4){0.f, 0.f, 0.f, 0.f};

    const int nt = 512 >> 5;

    auto stage = [&](int buf, int t) {
        long k0 = (long)t << 5;
        #pragma unroll
        for (int i = 0; i < 2; ++i) {
            int la = tid + i * 256;
            int row = la & 127, c = la >> 7;
            gload16(Xb + row * 512 + k0 + c * 8, (f16*)As[buf] + (size_t)la * 8);
        }
        #pragma unroll
        for (int i = 0; i < 2; ++i) {
            int la = tid + i * 256;
            int col = la & 127, c = la >> 7;
            gload16(W0 + (n0 + col) * 512 + k0 + c * 8,
                    (f16*)Bs[buf] + (size_t)la * 8);
        }
    };

    stage(0, 0);
    for (int t = 0; t < nt; ++t) {
        int cur = t & 1;
        __syncthreads();
        if (t + 1 < nt) stage(cur ^ 1, t + 1);
        const int g = l >> 4, idx = l & 15;
        half8 bf[4];
        #pragma unroll
        for (int ct = 0; ct < 4; ++ct)
            bf[ct] = *(const half8*)&Bs[cur][g][wc * 64 + ct * 16 + idx][0];
        #pragma unroll
        for (int rt = 0; rt < 4; ++rt) {
            half8 af = *(const half8*)&As[cur][g][wr * 64 + rt * 16 + idx][0];
            #pragma unroll
            for (int ct = 0; ct < 4; ++ct)
                acc[rt][ct] = __builtin_amdgcn_mfma_f32_16x16x32_f16(af, bf[ct], acc[rt][ct], 0, 0, 0);
        }
    }

    #pragma unroll
    for (int rt = 0; rt < 4; ++rt)
        #pragma unroll
        for (int ct = 0; ct < 4; ++ct) {
            long col = n0 + wc * 64 + ct * 16 + (l & 15);
            #pragma unroll
            for (int j = 0; j < 4; ++j) {
                long row = wr * 64 + rt * 16 + (l >> 4) * 4 + j;
                size_t o = ((size_t)b * 128 + row) * 512 + col;
                mh[o] = (f16)acc[rt][ct][j];
            }
        }
}

// ---------------------------------------------------------------------------
// k_gruG: fused gate GEMMs + GRU pointwise (single-plane m).
//   phase 1: gi = m_hi @ Wih^T  (1-pass, K=512)
//   phase 2: gh = h_hi @ Whh^T  (1-pass, K=512)
//   r,z accumulate gi+gh into same acc; n kept separate (ni, nh).
// 40KB LDS -> 4 blocks/CU.
// ---------------------------------------------------------------------------
__global__ __launch_bounds__(256, 4)
void k_gruG(const f16* __restrict__ mh,
            const f16* __restrict__ Wih,
            const f16* __restrict__ hih, const f16* __restrict__ hil,
            const f16* __restrict__ Whh,
            const float* __restrict__ bih, const float* __restrict__ bhh,
            f16* __restrict__ hoh, f16* __restrict__ hol,
            const float* __restrict__ nmask)
{
    __shared__ __align__(16) f16 As[2][4][128][8];   // 16KB [buf][g][row][8]
    __shared__ __align__(16) f16 Bs[2][4][192][8];   // 24KB [buf][g][cc][8]
    const int tid = threadIdx.x;
    const int l = tid & 63, w = tid >> 6;
    const int wr = w >> 1, wc = w & 1;
    const long m0 = (long)blockIdx.x * 128;
    const int  c0 = blockIdx.y * 64;

    f32x4 rz[2][4][2], ni[4][2], nh[4][2];
    #pragma unroll
    for (int rt = 0; rt < 4; ++rt)
        #pragma unroll
        for (int ct = 0; ct < 2; ++ct) {
            rz[0][rt][ct] = (f32x4){0.f, 0.f, 0.f, 0.f};
            rz[1][rt][ct] = (f32x4){0.f, 0.f, 0.f, 0.f};
            ni[rt][ct]    = (f32x4){0.f, 0.f, 0.f, 0.f};
            nh[rt][ct]    = (f32x4){0.f, 0.f, 0.f, 0.f};
        }

    auto stageB = [&](int buf, int t, const f16* W) {
        long k0 = (long)t << 5;
        #pragma unroll
        for (int i = 0; i < 3; ++i) {          // 768 chunks: 3 gates x 64 cols x 4 kq
            int la = tid + i * 256;
            int g = la / 192, cc = la - g * 192;
            int col = (cc >> 6) * 512 + c0 + (cc & 63);
            gload16(W + (size_t)col * 512 + k0 + g * 8,
                    (f16*)Bs[buf] + ((size_t)g * 192 + cc) * 8);
        }
    };
    auto stageA = [&](int buf, int t, const f16* X, int ldx) {
        long k0 = (long)t << 5;
        #pragma unroll
        for (int i = 0; i < 2; ++i) {
            int la = tid + i * 256;
            int g = la >> 7, row = la & 127;
            gload16(X + (size_t)(m0 + row) * ldx + k0 + g * 8,
                    (f16*)As[buf] + (size_t)la * 8);
        }
    };

    const int g = l >> 4, idx = l & 15;

    // ---- phase 1: gi ----
    stageA(0, 0, mh, 512); stageB(0, 0, Wih);
    for (int t = 0; t < 16; ++t) {
        int cur = t & 1;
        __syncthreads();
        if (t + 1 < 16) { stageA(cur ^ 1, t + 1, mh, 512); stageB(cur ^ 1, t + 1, Wih); }
        half8 bf[6];
        #pragma unroll
        for (int gc = 0; gc < 6; ++gc)
            bf[gc] = *(const half8*)&Bs[cur][g][(gc >> 1) * 64 + wc * 32 + (gc & 1) * 16 + idx][0];
        #pragma unroll
        for (int rt = 0; rt < 4; ++rt) {
            half8 ah = *(const half8*)&As[cur][g][wr * 64 + rt * 16 + idx][0];
            #pragma unroll
            for (int ct = 0; ct < 2; ++ct) {
                rz[0][rt][ct] = __builtin_amdgcn_mfma_f32_16x16x32_f16(ah, bf[ct],     rz[0][rt][ct], 0, 0, 0);
                rz[1][rt][ct] = __builtin_amdgcn_mfma_f32_16x16x32_f16(ah, bf[2 + ct], rz[1][rt][ct], 0, 0, 0);
                ni[rt][ct]    = __builtin_amdgcn_mfma_f32_16x16x32_f16(ah, bf[4 + ct], ni[rt][ct],    0, 0, 0);
            }
        }
    }
    __syncthreads();   // drain phase-1 reads before phase-2 restaging

    // ---- phase 2: gh ----
    stageA(0, 0, hih, 1024); stageB(0, 0, Whh);
    for (int t = 0; t < 16; ++t) {
        int cur = t & 1;
        __syncthreads();
        if (t + 1 < 16) { stageA(cur ^ 1, t + 1, hih, 1024); stageB(cur ^ 1, t + 1, Whh); }
        half8 bf[6];
        #pragma unroll
        for (int gc = 0; gc < 6; ++gc)
            bf[gc] = *(const half8*)&Bs[cur][g][(gc >> 1) * 64 + wc * 32 + (gc & 1) * 16 + idx][0];
        #pragma unroll
        for (int rt = 0; rt < 4; ++rt) {
            half8 ah = *(const half8*)&As[cur][g][wr * 64 + rt * 16 + idx][0];
            #pragma unroll
            for (int ct = 0; ct < 2; ++ct) {
                rz[0][rt][ct] = __builtin_amdgcn_mfma_f32_16x16x32_f16(ah, bf[ct],     rz[0][rt][ct], 0, 0, 0);
                rz[1][rt][ct] = __builtin_amdgcn_mfma_f32_16x16x32_f16(ah, bf[2 + ct], rz[1][rt][ct], 0, 0, 0);
                nh[rt][ct]    = __builtin_amdgcn_mfma_f32_16x16x32_f16(ah, bf[4 + ct], nh[rt][ct],    0, 0, 0);
            }
        }
    }

    // ---- epilogue: GRU ----
    #pragma unroll
    for (int rt = 0; rt < 4; ++rt)
        #pragma unroll
        for (int ct = 0; ct < 2; ++ct) {
            int c = c0 + wc * 32 + ct * 16 + idx;
            float br = bih[c]        + bhh[c];
            float bz = bih[512 + c]  + bhh[512 + c];
            float bni = bih[1024 + c];
            float bnh = bhh[1024 + c];
            #pragma unroll
            for (int j = 0; j < 4; ++j) {
                long row = m0 + wr * 64 + rt * 16 + g * 4 + j;
                float r = 1.f / (1.f + expf(-(rz[0][rt][ct][j] + br)));
                float z = 1.f / (1.f + expf(-(rz[1][rt][ct][j] + bz)));
                float n = tanhf(ni[rt][ct][j] + bni + r * (nh[rt][ct][j] + bnh));
                size_t o = (size_t)row * 1024 + c;
                float h_old = (float)hih[o] + (float)hil[o];
                float out = ((1.f - z) * n + z * h_old) * nmask[row];
                split_write(out, hoh + o, hol + o);
            }
        }
}

// ---------------------------------------------------------------------------
// dual-chain single-pass readout GEMM: blockIdx.z selects param set.
// OUT: 0 = fp32 + bias; 1 = f16 + bias + relu.
// ---------------------------------------------------------------------------
struct RP {
    const f16* X[2];  int ldx[2];
    const f16* W[2];  int ldw[2];
    const float* bias[2];
    float* Cf[2];  f16* Ch[2];
    int ldc[2];  int ncmax[2];  int K[2];
};
template<int OUT>
__global__ __launch_bounds__(256, 4)
void k_mfmaD(RP p) {
    const int z = blockIdx.z;
    const f16* Xh = p.X[z];  const int ldx = p.ldx[z];
    const f16* Wh = p.W[z];  const int ldw = p.ldw[z];
    const float* bias = p.bias[z];
    const int ldc = p.ldc[z], ncmax = p.ncmax[z], K = p.K[z];

    __shared__ __align__(16) f16 As[2][4][128][8];
    __shared__ __align__(16) f16 Bs[2][4][128][8];
    const int tid = threadIdx.x;
    const int l = tid & 63, w = tid >> 6;
    const int wr = w >> 1, wc = w & 1;
    const long m0 = (long)blockIdx.x * 128;
    const long n0 = (long)blockIdx.y * 128;

    f32x4 acc[4][4];
    #pragma unroll
    for (int i = 0; i < 4; i++)
        #pragma unroll
        for (int j = 0; j < 4; j++)
            acc[i][j] = (f32x4){0.f, 0.f, 0.f, 0.f};

    const int nt = K >> 5;

    auto stage = [&](int buf, int t) {
        long k0 = (long)t << 5;
        #pragma unroll
        for (int i = 0; i < 2; ++i) {
            int la = tid + i * 256;
            int row = la & 127, c = la >> 7;
            gload16(Xh + (m0 + row) * ldx + k0 + c * 8,
                    (f16*)As[buf] + (size_t)la * 8);
        }
        #pragma unroll
        for (int i = 0; i < 2; ++i) {
            int la = tid + i * 256;
            int col = la & 127, c = la >> 7;
            gload16(Wh + (n0 + col) * ldw + k0 + c * 8,
                    (f16*)Bs[buf] + (size_t)la * 8);
        }
    };

    stage(0, 0);
    for (int t = 0; t < nt; ++t) {
        int cur = t & 1;
        __syncthreads();
        if (t + 1 < nt) stage(cur ^ 1, t + 1);
        const int g = l >> 4, idx = l & 15;
        half8 bf[4];
        #pragma unroll
        for (int ct = 0; ct < 4; ++ct)
            bf[ct] = *(const half8*)&Bs[cur][g][wc * 64 + ct * 16 + idx][0];
        #pragma unroll
        for (int rt = 0; rt < 4; ++rt) {
            half8 ah = *(const half8*)&As[cur][g][wr * 64 + rt * 16 + idx][0];
            #pragma unroll
            for (int ct = 0; ct < 4; ++ct)
                acc[rt][ct] = __builtin_amdgcn_mfma_f32_16x16x32_f16(ah, bf[ct], acc[rt][ct], 0, 0, 0);
        }
    }

    #pragma unroll
    for (int rt = 0; rt < 4; ++rt)
        #pragma unroll
        for (int ct = 0; ct < 4; ++ct) {
            long col = n0 + wc * 64 + ct * 16 + (l & 15);
            if (col < ncmax) {
                float bv = bias ? bias[col] : 0.f;
                #pragma unroll
                for (int j = 0; j < 4; ++j) {
                    long row = m0 + wr * 64 + rt * 16 + (l >> 4) * 4 + j;
                    float v = acc[rt][ct][j] + bv;
                    if (OUT == 0) {
                        p.Cf[z][row * ldc + col] = v;
                    } else {
                        p.Ch[z][row * ldc + col] = (f16)fmaxf(v, 0.f);
                    }
                }
            }
        }
}

__global__ void k_readout(const float* __restrict__ gp, const float* __restrict__ vp,
                          const float* __restrict__ rmask, float* __restrict__ out) {
    int b = blockIdx.x;
    int t = threadIdx.x;
    float a[TGT_];
    const float* gr = gp + ((size_t)b * N_ + t) * TGT_;
    const float* vr = vp + ((size_t)b * N_ + t) * TGT_;
    float mk = rmask[b * N_ + t];
    #pragma unroll
    for (int j = 0; j < TGT_; j++)
        a[j] = (1.f / (1.f + expf(-gr[j]))) * vr[j] * mk;
    __shared__ float red[128][TGT_];
    #pragma unroll
    for (int j = 0; j < TGT_; j++) red[t][j] = a[j];
    __syncthreads();
    for (int off = 64; off > 0; off >>= 1) {
        if (t < off)
            #pragma unroll
            for (int j = 0; j < TGT_; j++) red[t][j] += red[t + off][j];
        __syncthreads();
    }
    if (t < TGT_) out[b * TGT_ + t] = red[0][t];
}

// ---------------------------------------------------------------------------
extern "C" void kernel_launch(void* const* d_in, const int* in_sizes, int n_in,
                              void* d_out, int out_size, void* d_ws, size_t ws_size,
                              hipStream_t stream) {
    const float* g    = (const float*)d_in[0];
    const float* h_in = (const float*)d_in[1];
    const float* e    = (const float*)d_in[2];
    const float* A    = (const float*)d_in[3];
    const float* Wih  = (const float*)d_in[4];
    const float* Whh  = (const float*)d_in[5];
    const float* bih  = (const float*)d_in[6];
    const float* bhh  = (const float*)d_in[7];

    const float *r1W[4], *r1b[4], *r2W[4], *r2b[4];
    bool interleaved = (in_sizes[10] == 128 * 512);
    if (interleaved) {
        for (int i = 0; i < 4; i++) {
            r1W[i] = (const float*)d_in[8 + 4 * i + 0];
            r1b[i] = (const float*)d_in[8 + 4 * i + 1];
            r2W[i] = (const float*)d_in[8 + 4 * i + 2];
            r2b[i] = (const float*)d_in[8 + 4 * i + 3];
        }
    } else {
        for (int i = 0; i < 4; i++) {
            r1W[i] = (const float*)d_in[8 + 2 * i + 0];
            r1b[i] = (const float*)d_in[8 + 2 * i + 1];
            r2W[i] = (const float*)d_in[16 + 2 * i + 0];
            r2b[i] = (const float*)d_in[16 + 2 * i + 1];
        }
    }

    char* ws = (char*)d_ws;
    size_t off = 0;
    auto alloc = [&](size_t bytes) { char* p = ws + off; off += bytes; return p; };

    f16* hbh[2]; f16* hbl[2];
    hbh[0] = (f16*)alloc((size_t)ROWS_ * 1024 * 2);
    hbl[0] = (f16*)alloc((size_t)ROWS_ * 1024 * 2);
    hbh[1] = (f16*)alloc((size_t)ROWS_ * 1024 * 2);
    hbl[1] = (f16*)alloc((size_t)ROWS_ * 1024 * 2);
    f16* mh = (f16*)alloc((size_t)ROWS_ * 512 * 2);
    f16* Mm = (f16*)alloc((size_t)ROWS_ * 512 * 2);
    char* hat = alloc((size_t)4 * 512 * 8192 * 2);   // 33.6MB union (hAT hi)
    f16*  hATh = (f16*)hat;
    // readout temps union into hat (hAT dead after last aggm): two chains
    f16*   ta1 = (f16*)hat;
    f16*   tb1 = ta1 + (size_t)ROWS_ * 128;
    f16*   ta2 = tb1 + (size_t)ROWS_ * 256;
    f16*   tb2 = ta2 + (size_t)ROWS_ * 128;
    float* gp  = (float*)(tb2 + (size_t)ROWS_ * 256);
    float* vp  = gp + (size_t)ROWS_ * TGT_;
    f16* ATh  = (f16*)alloc((size_t)512 * 2048 * 2);
    f16* Wihh = (f16*)alloc((size_t)1536 * 512 * 2);
    f16* Whhh = (f16*)alloc((size_t)1536 * 512 * 2);
    f16* rWh[8];
    const int rNc[8]  = {128, 256, 128, TGT_, 128, 256, 128, TGT_};
    const int rNcp[8] = {128, 256, 128, 128,  128, 256, 128, 128};
    const int rK[8]   = {1024, 128, 256, 128, 512, 128, 256, 128};
    for (int i = 0; i < 8; i++)
        rWh[i] = (f16*)alloc((size_t)rNcp[i] * rK[i] * 2);
    float* nm = (float*)alloc(ROWS_ * 4);
    float* rm = (float*)alloc(ROWS_ * 4);
    (void)ws_size;

    // ---- setup ----
    k_convA<<<(512 * 2048) / 256, 256, 0, stream>>>(A, ATh);
    {
        WSet wset;
        const float* srcs[10] = {Wih, Whh, r1W[0], r1W[1], r1W[2], r1W[3],
                                 r2W[0], r2W[1], r2W[2], r2W[3]};
        f16* dsts[10] = {Wihh, Whhh, rWh[0], rWh[1], rWh[2], rWh[3],
                         rWh[4], rWh[5], rWh[6], rWh[7]};
        int ncs[10]  = {1536, 1536, rNc[0], rNc[1], rNc[2], rNc[3], rNc[4], rNc[5], rNc[6], rNc[7]};
        int ncps[10] = {1536, 1536, rNcp[0], rNcp[1], rNcp[2], rNcp[3], rNcp[4], rNcp[5], rNcp[6], rNcp[7]};
        int ks[10]   = {512, 512, rK[0], rK[1], rK[2], rK[3], rK[4], rK[5], rK[6], rK[7]};
        for (int i = 0; i < 10; i++) {
            wset.s[i] = srcs[i]; wset.d[i] = dsts[i];
            wset.nc[i] = ncs[i]; wset.ncp[i] = ncps[i]; wset.kk[i] = ks[i];
        }
        int maxblocks = (1536 * 512 + 255) / 256;
        k_convWs<<<dim3(maxblocks, 10), 256, 0, stream>>>(wset);
    }
    k_mkmask<<<((long)ROWS_ * 512 + 255) / 256, 256, 0, stream>>>(g, e, Mm);
    k_init<<<ROWS_, 128, 0, stream>>>(h_in, hbh[0], hbl[0], nm, rm);

    // ---- recurrence (h ping-pongs, ends in hb[0]) ----
    for (int step = 0; step < NSTEPS_; step++) {
        int cur = step & 1, nxt = cur ^ 1;
        k_proj<<<dim3(4, 64, 4), 256, 0, stream>>>(ATh, hbh[cur], hATh);
        k_aggm<<<dim3(4, 64), 256, 0, stream>>>(Mm, hATh, mh);
        k_gruG<<<dim3(64, 8), 256, 0, stream>>>(mh, Wihh, hbh[cur], hbl[cur],
                                                Whhh, bih, bhh, hbh[nxt], hbl[nxt], nm);
    }

    // ---- readout: both MLP chains per dispatch via blockIdx.z ----
    auto setRP = [&](RP& p, int zi, const f16* X, int ldx, const f16* W, int ldw,
                     const float* bias, float* Cf, f16* Ch, int ldc, int ncmax, int K) {
        p.X[zi] = X; p.ldx[zi] = ldx; p.W[zi] = W; p.ldw[zi] = ldw;
        p.bias[zi] = bias; p.Cf[zi] = Cf; p.Ch[zi] = Ch;
        p.ldc[zi] = ldc; p.ncmax[zi] = ncmax; p.K[zi] = K;
    };
    RP p0, p1, p2, p3;
    setRP(p0, 0, hbh[0], 1024, rWh[0], 1024, r1b[0], nullptr, ta1, 128, 128, 1024);
    setRP(p0, 1, hbh[0], 1024, rWh[4],  512, r2b[0], nullptr, ta2, 128, 128,  512);
    setRP(p1, 0, ta1, 128, rWh[1], 128, r1b[1], nullptr, tb1, 256, 256, 128);
    setRP(p1, 1, ta2, 128, rWh[5], 128, r2b[1], nullptr, tb2, 256, 256, 128);
    setRP(p2, 0, tb1, 256, rWh[2], 256, r1b[2], nullptr, ta1, 128, 128, 256);
    setRP(p2, 1, tb2, 256, rWh[6], 256, r2b[2], nullptr, ta2, 128, 128, 256);
    setRP(p3, 0, ta1, 128, rWh[3], 128, r1b[3], gp, nullptr, TGT_, TGT_, 128);
    setRP(p3, 1, ta2, 128, rWh[7], 128, r2b[3], vp, nullptr, TGT_, TGT_, 128);
    k_mfmaD<1><<<dim3(64, 1, 2), 256, 0, stream>>>(p0);
    k_mfmaD<1><<<dim3(64, 2, 2), 256, 0, stream>>>(p1);
    k_mfmaD<1><<<dim3(64, 1, 2), 256, 0, stream>>>(p2);
    k_mfmaD<0><<<dim3(64, 1, 2), 256, 0, stream>>>(p3);

    k_readout<<<B_, 128, 0, stream>>>(gp, vp, rm, (float*)d_out);
}